// Round 7
// baseline (132.807 us; speedup 1.0000x reference)
//
#include <hip/hip_runtime.h>
#include <cstdint>
#include <cstddef>

// Problem constants
#define BATCH 8
#define CDIM  512
#define NPIX  4096   // 64*64
#define NHEAD 8
#define DH    64
#define KTOK  64
#define MEM   512

typedef __attribute__((ext_vector_type(8))) short          bf8;   // MFMA A/B operand (8 bf16)
typedef __attribute__((ext_vector_type(4))) float          f4;    // MFMA C/D
typedef __attribute__((ext_vector_type(4))) unsigned short us4;   // 8-byte bf16 pack

__device__ __forceinline__ unsigned short f2bf(float f){
  union { float f; unsigned int u; } x; x.f = f;
  unsigned int r = (x.u + 0x7fffu + ((x.u >> 16) & 1u)) >> 16;
  return (unsigned short)r;
}

// async global->LDS DMA, 16B per lane; LDS dest = wave-uniform base + lane*16
__device__ __forceinline__ void gld_lds16(const unsigned short* g, unsigned short* lds){
  __builtin_amdgcn_global_load_lds((const __attribute__((address_space(1))) unsigned int*)g,
                                   (__attribute__((address_space(3))) unsigned int*)lds, 16, 0, 0);
}

// ---------------- K0: weights fp32 -> bf16 ----------------
__global__ __launch_bounds__(256) void wconv(const float* __restrict__ wq, const float* __restrict__ wp,
                                             unsigned short* __restrict__ wqb, unsigned short* __restrict__ wpb){
  int i = (blockIdx.x * 256 + threadIdx.x) * 4;   // grid 256 -> covers 262144
  float4 a = *(const float4*)(wq + i);
  us4 pa = { f2bf(a.x), f2bf(a.y), f2bf(a.z), f2bf(a.w) };
  *(us4*)(wqb + i) = pa;
  float4 b = *(const float4*)(wp + i);
  us4 pb = { f2bf(b.x), f2bf(b.y), f2bf(b.z), f2bf(b.w) };
  *(us4*)(wpb + i) = pb;
}

// ---------------- K0b: x [b][c][n] fp32 -> xb [b][n][c] bf16 ----------------
__global__ __launch_bounds__(256) void xtrans(const float* __restrict__ x, unsigned short* __restrict__ xb){
  __shared__ __align__(16) unsigned short t[64 * 68];
  int tid = threadIdx.x;
  int n0 = blockIdx.x * 64, c0 = blockIdx.y * 64, b = blockIdx.z;
  const float* xp = x + ((size_t)(b * CDIM + c0)) * NPIX + n0;
#pragma unroll
  for (int it = 0; it < 4; ++it){
    int idx = it * 1024 + tid * 4;
    int cc = idx >> 6, nn = idx & 63;
    float4 v = *(const float4*)(xp + (size_t)cc * NPIX + nn);
    us4 pk = { f2bf(v.x), f2bf(v.y), f2bf(v.z), f2bf(v.w) };
    *(us4*)&t[cc * 68 + nn] = pk;
  }
  __syncthreads();
  unsigned short* op = xb + ((size_t)(b * NPIX + n0)) * CDIM + c0;
#pragma unroll
  for (int it = 0; it < 4; ++it){
    int idx = it * 1024 + tid * 4;
    int nn = idx >> 6, c4 = idx & 63;
    us4 pk = { t[(c4 + 0) * 68 + nn], t[(c4 + 1) * 68 + nn],
               t[(c4 + 2) * 68 + nn], t[(c4 + 3) * 68 + nn] };
    *(us4*)(op + (size_t)nn * CDIM + c4) = pk;
  }
}

// ---------------- K1: K/V projection (fp32 compute, bf16 out) ----------------
__global__ __launch_bounds__(256) void kvproj(const float* __restrict__ Ft, const float* __restrict__ Wk,
                                              const float* __restrict__ Wv, unsigned short* __restrict__ kb,
                                              unsigned short* __restrict__ vt){
  __shared__ float ft[8][MEM];
  int tid = threadIdx.x;
  int cg = blockIdx.x, kk0 = blockIdx.y * 8, b = blockIdx.z;
  const float* fp = Ft + ((size_t)(b * KTOK + kk0)) * MEM;
#pragma unroll
  for (int it = 0; it < 4; ++it){
    int idx = it * 1024 + tid * 4;
    int row = idx >> 9, m = idx & 511;
    *(float4*)&ft[row][m] = *(const float4*)(fp + (size_t)row * MEM + m);
  }
  __syncthreads();
  int kv = tid >> 7, cl = tid & 127;
  int c = cg * 128 + cl;
  const float* wrow = (kv ? Wv : Wk) + (size_t)c * MEM;
  float acc[8] = {0.f,0.f,0.f,0.f,0.f,0.f,0.f,0.f};
  for (int m = 0; m < MEM; m += 4){
    float4 wv4 = *(const float4*)(wrow + m);
#pragma unroll
    for (int kk = 0; kk < 8; ++kk){
      acc[kk] += wv4.x * ft[kk][m] + wv4.y * ft[kk][m+1] + wv4.z * ft[kk][m+2] + wv4.w * ft[kk][m+3];
    }
  }
  int h = c >> 6, dd = c & 63;
  if (kv == 0){
#pragma unroll
    for (int kk = 0; kk < 8; ++kk)
      kb[(((size_t)(b * NHEAD + h)) * KTOK + kk0 + kk) * DH + dd] = f2bf(acc[kk] * 0.125f);
  } else {
#pragma unroll
    for (int kk = 0; kk < 8; ++kk)
      vt[(((size_t)(b * NHEAD + h)) * DH + dd) * KTOK + kk0 + kk] = f2bf(acc[kk]);
  }
}

// =========== shared GEMM building blocks: 128x128 tile, BK=32, double-buffered ===========
// LDS: buf p in [p*8192, p*8192+8192): A [0,4096) + B [4096,8192) shorts.
// Tile layout [128 rows][32 shorts], 16B chunks XOR-swizzled: phys_chunk = logical ^ (row&3).
// STAGE: 16 DMAs/block (4/wave): wave w covers 16-row groups {w, w+4} of A and B.
#define GEMM_PRE(APTR, BPTR)                                                              \
  const int arow = l >> 2;                                                                \
  const int achk = (l & 3) ^ (arow & 3);                                                  \
  const unsigned short* aS = (APTR) + (size_t)(o0 + w * 16 + arow) * CDIM + achk * 8;     \
  const unsigned short* bS = (BPTR) + ((size_t)(b * NPIX) + n0 + w * 16 + arow) * CDIM + achk * 8;

#define STAGE(p, kc)                                                                      \
  {                                                                                       \
    _Pragma("unroll")                                                                     \
    for (int j = 0; j < 2; ++j){                                                          \
      gld_lds16(aS + (size_t)j * 64 * CDIM + (kc), &ab[(p) * 8192 + (w + j * 4) * 512]);  \
      gld_lds16(bS + (size_t)j * 64 * CDIM + (kc), &ab[(p) * 8192 + 4096 + (w + j * 4) * 512]); \
    }                                                                                     \
  }

#define GEMM_STEP(p, ACC)                                                                 \
  {                                                                                       \
    bf8 af[4], bfr[4];                                                                    \
    _Pragma("unroll")                                                                     \
    for (int fi = 0; fi < 4; ++fi){                                                       \
      int r = ol + fi * 16 + lo;                                                          \
      af[fi] = *(const bf8*)&ab[(p) * 8192 + r * 32 + ((hi ^ (r & 3)) << 3)];             \
    }                                                                                     \
    _Pragma("unroll")                                                                     \
    for (int fj = 0; fj < 4; ++fj){                                                       \
      int r = nl + fj * 16 + lo;                                                          \
      bfr[fj] = *(const bf8*)&ab[(p) * 8192 + 4096 + r * 32 + ((hi ^ (r & 3)) << 3)];     \
    }                                                                                     \
    _Pragma("unroll")                                                                     \
    for (int fi = 0; fi < 4; ++fi)                                                        \
      _Pragma("unroll")                                                                   \
      for (int fj = 0; fj < 4; ++fj)                                                      \
        ACC[fi][fj] = __builtin_amdgcn_mfma_f32_16x16x32_bf16(af[fi], bfr[fj], ACC[fi][fj], 0, 0, 0); \
  }

// ---------------- K2a: q projection GEMM (bf16 out, [b][n][c]) ----------------
__global__ __launch_bounds__(256, 4) void qgemm(const unsigned short* __restrict__ wqb,
                                                const unsigned short* __restrict__ xb,
                                                unsigned short* __restrict__ qb){
  __shared__ __align__(16) unsigned short ab[16384];   // 32 KB, 2 x (A+B)
  int tid = threadIdx.x;
  int w = tid >> 6, l = tid & 63;
  int lo = l & 15, hi = l >> 4;
  int n0 = blockIdx.x * 128, o0 = blockIdx.y * 128, b = blockIdx.z;
  int ol = (w >> 1) * 64, nl = (w & 1) * 64;

  f4 z = {0.f, 0.f, 0.f, 0.f};
  f4 acc[4][4];
#pragma unroll
  for (int i = 0; i < 4; ++i)
#pragma unroll
    for (int j = 0; j < 4; ++j) acc[i][j] = z;

  GEMM_PRE(wqb, xb)

  STAGE(0, 0)
  __syncthreads();                 // buf0 landed
  int cur = 0;
  for (int t = 0; t < 16; ++t){
    if (t < 15) STAGE(cur ^ 1, (t + 1) * 32)   // next tile flies during compute
    GEMM_STEP(cur, acc)
    __syncthreads();               // next buf landed; current reads done (WAR)
    cur ^= 1;
  }

  // q[b][n][c]; D-layout row(o)=fi*16+hi*4+r, col(n)=fj*16+lo
  unsigned short* op = qb + ((size_t)(b * NPIX) + n0 + nl) * CDIM + o0 + ol;
#pragma unroll
  for (int fi = 0; fi < 4; ++fi)
#pragma unroll
    for (int fj = 0; fj < 4; ++fj){
      f4 v = acc[fi][fj];
      us4 pk = { f2bf(v[0]), f2bf(v[1]), f2bf(v[2]), f2bf(v[3]) };
      *(us4*)(op + (size_t)(fj * 16 + lo) * CDIM + fi * 16 + hi * 4) = pk;
    }
}

// ---------------- K2b: attention (barrier-free; att overwrites q in place) ----------------
// Each wave: one head, 64 q-rows. k/v/q fragments direct from global (L2/L3-resident).
__global__ __launch_bounds__(256, 4) void attn(const unsigned short* __restrict__ qb,
                                               const unsigned short* __restrict__ kb,
                                               const unsigned short* __restrict__ vt,
                                               unsigned short* __restrict__ att){
  __shared__ __align__(16) unsigned short pb[16384];   // 4 waves x [64][64] swizzled P
  int tid = threadIdx.x;
  int w = tid >> 6, l = tid & 63;
  int lo = l & 15, hi = l >> 4;
  int n0 = blockIdx.x * 256 + w * 64;
  int head = blockIdx.y, b = blockIdx.z;

  const unsigned short* qh = qb + ((size_t)(b * NPIX) + n0) * CDIM + head * 64;
  const unsigned short* kh = kb + (size_t)(b * NHEAD + head) * (KTOK * DH);
  const unsigned short* vh = vt + (size_t)(b * NHEAD + head) * (DH * KTOK);
  unsigned short* P = &pb[w * 4096];

  f4 z = {0.f, 0.f, 0.f, 0.f};
  // S^T[kk][n] = sum_dd k[kk][dd] * q[n][dd] ; kb pre-scaled by 1/sqrt(d)
  f4 accs[4][4];
#pragma unroll
  for (int i = 0; i < 4; ++i)
#pragma unroll
    for (int j = 0; j < 4; ++j) accs[i][j] = z;
#pragma unroll
  for (int ks = 0; ks < 2; ++ks){
    bf8 ka[4];
#pragma unroll
    for (int fi = 0; fi < 4; ++fi)
      ka[fi] = *(const bf8*)(kh + (fi * 16 + lo) * 64 + ks * 32 + hi * 8);
#pragma unroll
    for (int fj = 0; fj < 4; ++fj){
      bf8 qf = *(const bf8*)(qh + (size_t)(fj * 16 + lo) * CDIM + ks * 32 + hi * 8);
#pragma unroll
      for (int fi = 0; fi < 4; ++fi)
        accs[fi][fj] = __builtin_amdgcn_mfma_f32_16x16x32_bf16(ka[fi], qf, accs[fi][fj], 0, 0, 0);
    }
  }

  // Softmax over kk (per n-column): 16 local (fi x r) + shuffles l^16, l^32; P -> LDS (swizzled)
#pragma unroll
  for (int fj = 0; fj < 4; ++fj){
    float mx = accs[0][fj][0];
#pragma unroll
    for (int fi = 0; fi < 4; ++fi)
#pragma unroll
      for (int r = 0; r < 4; ++r) mx = fmaxf(mx, accs[fi][fj][r]);
    mx = fmaxf(mx, __shfl_xor(mx, 16));
    mx = fmaxf(mx, __shfl_xor(mx, 32));
    float sm = 0.f;
#pragma unroll
    for (int fi = 0; fi < 4; ++fi)
#pragma unroll
      for (int r = 0; r < 4; ++r){
        float e = __expf(accs[fi][fj][r] - mx);
        accs[fi][fj][r] = e; sm += e;
      }
    sm += __shfl_xor(sm, 16);
    sm += __shfl_xor(sm, 32);
    float inv = 1.0f / sm;
#pragma unroll
    for (int fi = 0; fi < 4; ++fi){
      us4 pk = { f2bf(accs[fi][fj][0] * inv), f2bf(accs[fi][fj][1] * inv),
                 f2bf(accs[fi][fj][2] * inv), f2bf(accs[fi][fj][3] * inv) };
      int row = fj * 16 + lo;                  // n
      int col = fi * 16 + hi * 4;              // kk
      int cs  = (((col >> 3) ^ (row & 7)) << 3) | (col & 7);
      *(us4*)&P[row * 64 + cs] = pk;
    }
  }

  // out^T[dd][n] = sum_kk vt[dd][kk] * P[n][kk]
  f4 acco[4][4];
#pragma unroll
  for (int i = 0; i < 4; ++i)
#pragma unroll
    for (int j = 0; j < 4; ++j) acco[i][j] = z;
#pragma unroll
  for (int ks = 0; ks < 2; ++ks){
    int sw = (((ks * 4 + hi) ^ (lo & 7)) << 3);
    bf8 va[4];
#pragma unroll
    for (int fi = 0; fi < 4; ++fi)
      va[fi] = *(const bf8*)(vh + (fi * 16 + lo) * 64 + ks * 32 + hi * 8);
#pragma unroll
    for (int fj = 0; fj < 4; ++fj){
      bf8 pf = *(const bf8*)&P[(fj * 16 + lo) * 64 + sw];
#pragma unroll
      for (int fi = 0; fi < 4; ++fi)
        acco[fi][fj] = __builtin_amdgcn_mfma_f32_16x16x32_bf16(va[fi], pf, acco[fi][fj], 0, 0, 0);
    }
  }

  // att overwrites q in place (att == qb buffer): wave owns this (rows, head-slice) tile,
  // and every store data-depends on this wave's q loads -> safe.
  unsigned short* op = att + ((size_t)(b * NPIX) + n0) * CDIM + head * 64;
#pragma unroll
  for (int fi = 0; fi < 4; ++fi)
#pragma unroll
    for (int fj = 0; fj < 4; ++fj){
      f4 v = acco[fi][fj];
      us4 pk = { f2bf(v[0]), f2bf(v[1]), f2bf(v[2]), f2bf(v[3]) };
      *(us4*)(op + (size_t)(fj * 16 + lo) * CDIM + fi * 16 + hi * 4) = pk;
    }
}

// ---------------- K3: output projection + bias + residual ----------------
__global__ __launch_bounds__(256, 4) void pproj(const unsigned short* __restrict__ wpb,
                                                const unsigned short* __restrict__ att,
                                                const float* __restrict__ x,
                                                const float* __restrict__ bpv,
                                                float* __restrict__ out){
  __shared__ __align__(16) unsigned short ab[16384];   // 32 KB, 2 x (A+B)
  int tid = threadIdx.x;
  int w = tid >> 6, l = tid & 63;
  int lo = l & 15, hi = l >> 4;
  int n0 = blockIdx.x * 128, o0 = blockIdx.y * 128, b = blockIdx.z;
  int ol = (w >> 1) * 64, nl = (w & 1) * 64;

  f4 z = {0.f, 0.f, 0.f, 0.f};
  f4 acc[4][4];
#pragma unroll
  for (int i = 0; i < 4; ++i)
#pragma unroll
    for (int j = 0; j < 4; ++j) acc[i][j] = z;

  GEMM_PRE(wpb, att)

  STAGE(0, 0)
  __syncthreads();
  int cur = 0;
  for (int t = 0; t < 16; ++t){
    if (t < 15) STAGE(cur ^ 1, (t + 1) * 32)
    GEMM_STEP(cur, acc)
    __syncthreads();
    cur ^= 1;
  }

#pragma unroll
  for (int fi = 0; fi < 4; ++fi)
#pragma unroll
    for (int fj = 0; fj < 4; ++fj){
      int o = o0 + ol + fi * 16 + hi * 4;
      int n = n0 + nl + fj * 16 + lo;
#pragma unroll
      for (int r = 0; r < 4; ++r){
        size_t idx = ((size_t)(b * CDIM + o + r)) * NPIX + n;
        out[idx] = acc[fi][fj][r] + bpv[o + r] + x[idx];
      }
    }
}

extern "C" void kernel_launch(void* const* d_in, const int* in_sizes, int n_in,
                              void* d_out, int out_size, void* d_ws, size_t ws_size,
                              hipStream_t stream){
  const float* x  = (const float*)d_in[0];
  const float* Ft = (const float*)d_in[1];
  const float* Wq = (const float*)d_in[2];
  const float* Wk = (const float*)d_in[3];
  const float* Wv = (const float*)d_in[4];
  const float* Wp = (const float*)d_in[5];
  const float* bp = (const float*)d_in[6];
  float* out = (float*)d_out;

  char* ws = (char*)d_ws;
  // ws layout (bytes): wqb 512K | wpb 512K | xb 32M | qb/att 32M | kb 512K | vt 512K (~66MB)
  unsigned short* wqb = (unsigned short*)(ws);
  unsigned short* wpb = (unsigned short*)(ws + 524288);
  unsigned short* xb  = (unsigned short*)(ws + 1048576);
  unsigned short* qb  = (unsigned short*)(ws + 1048576 + 33554432);   // q, overwritten by att
  unsigned short* kb  = (unsigned short*)(ws + 1048576 + 2ull * 33554432);
  unsigned short* vt  = (unsigned short*)(ws + 1048576 + 2ull * 33554432 + 524288);

  wconv<<<dim3(256), dim3(256), 0, stream>>>(Wq, Wp, wqb, wpb);
  xtrans<<<dim3(64, 8, 8), dim3(256), 0, stream>>>(x, xb);
  kvproj<<<dim3(4, 8, 8), dim3(256), 0, stream>>>(Ft, Wk, Wv, kb, vt);
  qgemm<<<dim3(32, 4, 8), dim3(256), 0, stream>>>(wqb, xb, qb);
  attn<<<dim3(16, 8, 8), dim3(256), 0, stream>>>(qb, kb, vt, qb);
  pproj<<<dim3(32, 4, 8), dim3(256), 0, stream>>>(wpb, qb, x, bp, out);
}

// Round 9
// 125.965 us; speedup vs baseline: 1.0543x; 1.0543x over previous
//
#include <hip/hip_runtime.h>
#include <cstdint>
#include <cstddef>

// Problem constants
#define BATCH 8
#define CDIM  512
#define NPIX  4096   // 64*64
#define NHEAD 8
#define DH    64
#define KTOK  64
#define MEM   512

typedef __attribute__((ext_vector_type(8))) short          bf8;   // MFMA A/B operand (8 bf16)
typedef __attribute__((ext_vector_type(4))) float          f4;    // MFMA C/D
typedef __attribute__((ext_vector_type(4))) unsigned short us4;   // 8-byte bf16 pack

__device__ __forceinline__ unsigned short f2bf(float f){
  union { float f; unsigned int u; } x; x.f = f;
  unsigned int r = (x.u + 0x7fffu + ((x.u >> 16) & 1u)) >> 16;
  return (unsigned short)r;
}

// async global->LDS DMA, 16B per lane; LDS dest = wave-uniform base + lane*16
__device__ __forceinline__ void gld_lds16(const unsigned short* g, unsigned short* lds){
  __builtin_amdgcn_global_load_lds((const __attribute__((address_space(1))) unsigned int*)g,
                                   (__attribute__((address_space(3))) unsigned int*)lds, 16, 0, 0);
}

// ---------------- K0: weights fp32 -> bf16 ----------------
__global__ __launch_bounds__(256) void wconv(const float* __restrict__ wq, const float* __restrict__ wp,
                                             unsigned short* __restrict__ wqb, unsigned short* __restrict__ wpb){
  int i = (blockIdx.x * 256 + threadIdx.x) * 4;   // grid 256 -> covers 262144
  float4 a = *(const float4*)(wq + i);
  us4 pa = { f2bf(a.x), f2bf(a.y), f2bf(a.z), f2bf(a.w) };
  *(us4*)(wqb + i) = pa;
  float4 b = *(const float4*)(wp + i);
  us4 pb = { f2bf(b.x), f2bf(b.y), f2bf(b.z), f2bf(b.w) };
  *(us4*)(wpb + i) = pb;
}

// ---------------- K0b: x [b][c][n] fp32 -> xb [b][n][c] bf16 ----------------
__global__ __launch_bounds__(256) void xtrans(const float* __restrict__ x, unsigned short* __restrict__ xb){
  __shared__ __align__(16) unsigned short t[64 * 68];
  int tid = threadIdx.x;
  int n0 = blockIdx.x * 64, c0 = blockIdx.y * 64, b = blockIdx.z;
  const float* xp = x + ((size_t)(b * CDIM + c0)) * NPIX + n0;
#pragma unroll
  for (int it = 0; it < 4; ++it){
    int idx = it * 1024 + tid * 4;
    int cc = idx >> 6, nn = idx & 63;
    float4 v = *(const float4*)(xp + (size_t)cc * NPIX + nn);
    us4 pk = { f2bf(v.x), f2bf(v.y), f2bf(v.z), f2bf(v.w) };
    *(us4*)&t[cc * 68 + nn] = pk;
  }
  __syncthreads();
  unsigned short* op = xb + ((size_t)(b * NPIX + n0)) * CDIM + c0;
#pragma unroll
  for (int it = 0; it < 4; ++it){
    int idx = it * 1024 + tid * 4;
    int nn = idx >> 6, c4 = idx & 63;
    us4 pk = { t[(c4 + 0) * 68 + nn], t[(c4 + 1) * 68 + nn],
               t[(c4 + 2) * 68 + nn], t[(c4 + 3) * 68 + nn] };
    *(us4*)(op + (size_t)nn * CDIM + c4) = pk;
  }
}

// ---------------- K1: K/V projection (fp32 compute, bf16 out) ----------------
__global__ __launch_bounds__(256) void kvproj(const float* __restrict__ Ft, const float* __restrict__ Wk,
                                              const float* __restrict__ Wv, unsigned short* __restrict__ kb,
                                              unsigned short* __restrict__ vt){
  __shared__ float ft[8][MEM];
  int tid = threadIdx.x;
  int cg = blockIdx.x, kk0 = blockIdx.y * 8, b = blockIdx.z;
  const float* fp = Ft + ((size_t)(b * KTOK + kk0)) * MEM;
#pragma unroll
  for (int it = 0; it < 4; ++it){
    int idx = it * 1024 + tid * 4;
    int row = idx >> 9, m = idx & 511;
    *(float4*)&ft[row][m] = *(const float4*)(fp + (size_t)row * MEM + m);
  }
  __syncthreads();
  int kv = tid >> 7, cl = tid & 127;
  int c = cg * 128 + cl;
  const float* wrow = (kv ? Wv : Wk) + (size_t)c * MEM;
  float acc[8] = {0.f,0.f,0.f,0.f,0.f,0.f,0.f,0.f};
  for (int m = 0; m < MEM; m += 4){
    float4 wv4 = *(const float4*)(wrow + m);
#pragma unroll
    for (int kk = 0; kk < 8; ++kk){
      acc[kk] += wv4.x * ft[kk][m] + wv4.y * ft[kk][m+1] + wv4.z * ft[kk][m+2] + wv4.w * ft[kk][m+3];
    }
  }
  int h = c >> 6, dd = c & 63;
  if (kv == 0){
#pragma unroll
    for (int kk = 0; kk < 8; ++kk)
      kb[(((size_t)(b * NHEAD + h)) * KTOK + kk0 + kk) * DH + dd] = f2bf(acc[kk] * 0.125f);
  } else {
#pragma unroll
    for (int kk = 0; kk < 8; ++kk)
      vt[(((size_t)(b * NHEAD + h)) * DH + dd) * KTOK + kk0 + kk] = f2bf(acc[kk]);
  }
}

// ====== shared GEMM blocks: 128x128 tile, BK=64, double-buffered, conflict-free swizzle ======
// LDS: buf p at [p*16384, p*16384+16384): A [0,8192) + B [8192,16384) shorts.
// Tile [128 rows][64 shorts] (128B rows); 16B chunks XOR-swizzled: phys = logical ^ (row&7).
// STAGE: 32 DMAs/block (8/wave): wave w covers 8-row groups {w, w+4, w+8, w+12} of A and B.
// gld_lds writes lane l -> row l>>3, phys chunk l&7; source pre-swizzled chunk (l&7)^(l>>3).
#define GEMM_PRE(APTR, BPTR)                                                              \
  const int arow = l >> 3;                                                                \
  const int achk = (l & 7) ^ arow;                                                        \
  const unsigned short* aS = (APTR) + (size_t)(o0 + w * 8 + arow) * CDIM + achk * 8;      \
  const unsigned short* bS = (BPTR) + ((size_t)(b * NPIX) + n0 + w * 8 + arow) * CDIM + achk * 8;

#define STAGE(p, kc)                                                                      \
  {                                                                                       \
    _Pragma("unroll")                                                                     \
    for (int j = 0; j < 4; ++j){                                                          \
      gld_lds16(aS + (size_t)j * 32 * CDIM + (kc), &ab[(p) * 16384 + (w + j * 4) * 512]); \
      gld_lds16(bS + (size_t)j * 32 * CDIM + (kc), &ab[(p) * 16384 + 8192 + (w + j * 4) * 512]); \
    }                                                                                     \
  }

#define GEMM_STEP(p, ACC)                                                                 \
  _Pragma("unroll")                                                                       \
  for (int ks = 0; ks < 2; ++ks){                                                         \
    bf8 af[4], bfr[4];                                                                    \
    _Pragma("unroll")                                                                     \
    for (int fi = 0; fi < 4; ++fi){                                                       \
      int r = ol + fi * 16 + lo;                                                          \
      af[fi] = *(const bf8*)&ab[(p) * 16384 + r * 64 + (((ks * 4 + hi) ^ (r & 7)) << 3)]; \
    }                                                                                     \
    _Pragma("unroll")                                                                     \
    for (int fj = 0; fj < 4; ++fj){                                                       \
      int r = nl + fj * 16 + lo;                                                          \
      bfr[fj] = *(const bf8*)&ab[(p) * 16384 + 8192 + r * 64 + (((ks * 4 + hi) ^ (r & 7)) << 3)]; \
    }                                                                                     \
    _Pragma("unroll")                                                                     \
    for (int fi = 0; fi < 4; ++fi)                                                        \
      _Pragma("unroll")                                                                   \
      for (int fj = 0; fj < 4; ++fj)                                                      \
        ACC[fi][fj] = __builtin_amdgcn_mfma_f32_16x16x32_bf16(af[fi], bfr[fj], ACC[fi][fj], 0, 0, 0); \
  }

// ---------------- K2a: q projection GEMM (bf16 out, [b][n][c]) ----------------
__global__ __launch_bounds__(256, 2) void qgemm(const unsigned short* __restrict__ wqb,
                                                const unsigned short* __restrict__ xb,
                                                unsigned short* __restrict__ qb){
  __shared__ __align__(16) unsigned short ab[32768];   // 64 KB, 2 x (A+B)
  int tid = threadIdx.x;
  int w = tid >> 6, l = tid & 63;
  int lo = l & 15, hi = l >> 4;
  int n0 = blockIdx.x * 128, o0 = blockIdx.y * 128, b = blockIdx.z;
  int ol = (w >> 1) * 64, nl = (w & 1) * 64;

  f4 z = {0.f, 0.f, 0.f, 0.f};
  f4 acc[4][4];
#pragma unroll
  for (int i = 0; i < 4; ++i)
#pragma unroll
    for (int j = 0; j < 4; ++j) acc[i][j] = z;

  GEMM_PRE(wqb, xb)

  STAGE(0, 0)
  __syncthreads();                 // buf0 landed
  for (int t = 0; t < 8; ++t){
    int cur = t & 1;
    if (t < 7) STAGE(cur ^ 1, (t + 1) * 64)   // next tile flies during this tile's compute
    GEMM_STEP(cur, acc)
    __syncthreads();               // next buf landed; current reads done (WAR)
  }

  // q[b][n][c]; D-layout row(o)=fi*16+hi*4+r, col(n)=fj*16+lo
  unsigned short* op = qb + ((size_t)(b * NPIX) + n0 + nl) * CDIM + o0 + ol;
#pragma unroll
  for (int fi = 0; fi < 4; ++fi)
#pragma unroll
    for (int fj = 0; fj < 4; ++fj){
      f4 v = acc[fi][fj];
      us4 pk = { f2bf(v[0]), f2bf(v[1]), f2bf(v[2]), f2bf(v[3]) };
      *(us4*)(op + (size_t)(fj * 16 + lo) * CDIM + fi * 16 + hi * 4) = pk;
    }
}

// ---------------- K2b: attention (barrier-free; att overwrites q in place) ----------------
// Each wave: one head, 64 q-rows. k/v/q fragments direct from global (L2/L3-resident).
__global__ __launch_bounds__(256, 4) void attn(const unsigned short* __restrict__ qb,
                                               const unsigned short* __restrict__ kb,
                                               const unsigned short* __restrict__ vt,
                                               unsigned short* __restrict__ att){
  __shared__ __align__(16) unsigned short pb[16384];   // 4 waves x [64][64] swizzled P
  int tid = threadIdx.x;
  int w = tid >> 6, l = tid & 63;
  int lo = l & 15, hi = l >> 4;
  int n0 = blockIdx.x * 256 + w * 64;
  int head = blockIdx.y, b = blockIdx.z;

  const unsigned short* qh = qb + ((size_t)(b * NPIX) + n0) * CDIM + head * 64;
  const unsigned short* kh = kb + (size_t)(b * NHEAD + head) * (KTOK * DH);
  const unsigned short* vh = vt + (size_t)(b * NHEAD + head) * (DH * KTOK);
  unsigned short* P = &pb[w * 4096];

  f4 z = {0.f, 0.f, 0.f, 0.f};
  // S^T[kk][n] = sum_dd k[kk][dd] * q[n][dd] ; kb pre-scaled by 1/sqrt(d)
  f4 accs[4][4];
#pragma unroll
  for (int i = 0; i < 4; ++i)
#pragma unroll
    for (int j = 0; j < 4; ++j) accs[i][j] = z;
#pragma unroll
  for (int ks = 0; ks < 2; ++ks){
    bf8 ka[4];
#pragma unroll
    for (int fi = 0; fi < 4; ++fi)
      ka[fi] = *(const bf8*)(kh + (fi * 16 + lo) * 64 + ks * 32 + hi * 8);
#pragma unroll
    for (int fj = 0; fj < 4; ++fj){
      bf8 qf = *(const bf8*)(qh + (size_t)(fj * 16 + lo) * CDIM + ks * 32 + hi * 8);
#pragma unroll
      for (int fi = 0; fi < 4; ++fi)
        accs[fi][fj] = __builtin_amdgcn_mfma_f32_16x16x32_bf16(ka[fi], qf, accs[fi][fj], 0, 0, 0);
    }
  }

  // Softmax over kk (per n-column): 16 local (fi x r) + shuffles l^16, l^32; P -> LDS (swizzled)
#pragma unroll
  for (int fj = 0; fj < 4; ++fj){
    float mx = accs[0][fj][0];
#pragma unroll
    for (int fi = 0; fi < 4; ++fi)
#pragma unroll
      for (int r = 0; r < 4; ++r) mx = fmaxf(mx, accs[fi][fj][r]);
    mx = fmaxf(mx, __shfl_xor(mx, 16));
    mx = fmaxf(mx, __shfl_xor(mx, 32));
    float sm = 0.f;
#pragma unroll
    for (int fi = 0; fi < 4; ++fi)
#pragma unroll
      for (int r = 0; r < 4; ++r){
        float e = __expf(accs[fi][fj][r] - mx);
        accs[fi][fj][r] = e; sm += e;
      }
    sm += __shfl_xor(sm, 16);
    sm += __shfl_xor(sm, 32);
    float inv = 1.0f / sm;
#pragma unroll
    for (int fi = 0; fi < 4; ++fi){
      us4 pk = { f2bf(accs[fi][fj][0] * inv), f2bf(accs[fi][fj][1] * inv),
                 f2bf(accs[fi][fj][2] * inv), f2bf(accs[fi][fj][3] * inv) };
      int row = fj * 16 + lo;                  // n
      int col = fi * 16 + hi * 4;              // kk
      int cs  = (((col >> 3) ^ (row & 7)) << 3) | (col & 7);
      *(us4*)&P[row * 64 + cs] = pk;
    }
  }

  // out^T[dd][n] = sum_kk vt[dd][kk] * P[n][kk]
  f4 acco[4][4];
#pragma unroll
  for (int i = 0; i < 4; ++i)
#pragma unroll
    for (int j = 0; j < 4; ++j) acco[i][j] = z;
#pragma unroll
  for (int ks = 0; ks < 2; ++ks){
    int sw = (((ks * 4 + hi) ^ (lo & 7)) << 3);
    bf8 va[4];
#pragma unroll
    for (int fi = 0; fi < 4; ++fi)
      va[fi] = *(const bf8*)(vh + (fi * 16 + lo) * 64 + ks * 32 + hi * 8);
#pragma unroll
    for (int fj = 0; fj < 4; ++fj){
      bf8 pf = *(const bf8*)&P[(fj * 16 + lo) * 64 + sw];
#pragma unroll
      for (int fi = 0; fi < 4; ++fi)
        acco[fi][fj] = __builtin_amdgcn_mfma_f32_16x16x32_bf16(va[fi], pf, acco[fi][fj], 0, 0, 0);
    }
  }

  // att overwrites q in place (att == qb buffer): wave owns this (rows, head-slice) tile,
  // and every store data-depends on this wave's q loads -> safe.
  unsigned short* op = att + ((size_t)(b * NPIX) + n0) * CDIM + head * 64;
#pragma unroll
  for (int fi = 0; fi < 4; ++fi)
#pragma unroll
    for (int fj = 0; fj < 4; ++fj){
      f4 v = acco[fi][fj];
      us4 pk = { f2bf(v[0]), f2bf(v[1]), f2bf(v[2]), f2bf(v[3]) };
      *(us4*)(op + (size_t)(fj * 16 + lo) * CDIM + fi * 16 + hi * 4) = pk;
    }
}

// ---------------- K3: output projection + bias + residual ----------------
__global__ __launch_bounds__(256, 2) void pproj(const unsigned short* __restrict__ wpb,
                                                const unsigned short* __restrict__ att,
                                                const float* __restrict__ x,
                                                const float* __restrict__ bpv,
                                                float* __restrict__ out){
  __shared__ __align__(16) unsigned short ab[32768];   // 64 KB, 2 x (A+B)
  int tid = threadIdx.x;
  int w = tid >> 6, l = tid & 63;
  int lo = l & 15, hi = l >> 4;
  int n0 = blockIdx.x * 128, o0 = blockIdx.y * 128, b = blockIdx.z;
  int ol = (w >> 1) * 64, nl = (w & 1) * 64;

  f4 z = {0.f, 0.f, 0.f, 0.f};
  f4 acc[4][4];
#pragma unroll
  for (int i = 0; i < 4; ++i)
#pragma unroll
    for (int j = 0; j < 4; ++j) acc[i][j] = z;

  GEMM_PRE(wpb, att)

  STAGE(0, 0)
  __syncthreads();
  for (int t = 0; t < 8; ++t){
    int cur = t & 1;
    if (t < 7) STAGE(cur ^ 1, (t + 1) * 64)
    GEMM_STEP(cur, acc)
    __syncthreads();
  }

#pragma unroll
  for (int fi = 0; fi < 4; ++fi)
#pragma unroll
    for (int fj = 0; fj < 4; ++fj){
      int o = o0 + ol + fi * 16 + hi * 4;
      int n = n0 + nl + fj * 16 + lo;
#pragma unroll
      for (int r = 0; r < 4; ++r){
        size_t idx = ((size_t)(b * CDIM + o + r)) * NPIX + n;
        out[idx] = acc[fi][fj][r] + bpv[o + r] + x[idx];
      }
    }
}

extern "C" void kernel_launch(void* const* d_in, const int* in_sizes, int n_in,
                              void* d_out, int out_size, void* d_ws, size_t ws_size,
                              hipStream_t stream){
  const float* x  = (const float*)d_in[0];
  const float* Ft = (const float*)d_in[1];
  const float* Wq = (const float*)d_in[2];
  const float* Wk = (const float*)d_in[3];
  const float* Wv = (const float*)d_in[4];
  const float* Wp = (const float*)d_in[5];
  const float* bp = (const float*)d_in[6];
  float* out = (float*)d_out;

  char* ws = (char*)d_ws;
  // ws layout (bytes): wqb 512K | wpb 512K | xb 32M | qb/att 32M | kb 512K | vt 512K (~66MB)
  unsigned short* wqb = (unsigned short*)(ws);
  unsigned short* wpb = (unsigned short*)(ws + 524288);
  unsigned short* xb  = (unsigned short*)(ws + 1048576);
  unsigned short* qb  = (unsigned short*)(ws + 1048576 + 33554432);   // q, overwritten by att
  unsigned short* kb  = (unsigned short*)(ws + 1048576 + 2ull * 33554432);
  unsigned short* vt  = (unsigned short*)(ws + 1048576 + 2ull * 33554432 + 524288);

  wconv<<<dim3(256), dim3(256), 0, stream>>>(Wq, Wp, wqb, wpb);
  xtrans<<<dim3(64, 8, 8), dim3(256), 0, stream>>>(x, xb);
  kvproj<<<dim3(4, 8, 8), dim3(256), 0, stream>>>(Ft, Wk, Wv, kb, vt);
  qgemm<<<dim3(32, 4, 8), dim3(256), 0, stream>>>(wqb, xb, qb);
  attn<<<dim3(16, 8, 8), dim3(256), 0, stream>>>(qb, kb, vt, qb);
  pproj<<<dim3(32, 4, 8), dim3(256), 0, stream>>>(wpb, qb, x, bp, out);
}